// Round 14
// baseline (555.252 us; speedup 1.0000x reference)
//
#include <hip/hip_runtime.h>
#include <hip/hip_fp16.h>

#define S_LEN 8192
#define T_LEN 8192
#define D_DIM 256
#define QBLK 256
#define KVBLK 32
#define TSPLIT 8
#define NKV ((T_LEN / TSPLIT) / KVBLK)  // 32 tiles per block
#define NQT (S_LEN / QBLK)              // 32
#define KTILE_BYTES 16384               // 32 keys x 256 d x 2B (32x32 A-frag image)
#define VTILE_BYTES 16384               // 32 keys x 256 d x 2B (32x32 B-frag image)
#define RESCALE_THR 6.0f                // log2 domain
#define LOG2E 1.44269504f
// LDS: Kb 2x16KB @0 ; Vb 2x16KB @32768 -> 65536 B (1 block/CU)
#define SMEM_BYTES 65536

typedef _Float16 f16x8 __attribute__((ext_vector_type(8)));
typedef float f32x16 __attribute__((ext_vector_type(16)));

struct h4 { _Float16 h[4]; };

#define GLOAD_LDS16(g, l)                                              \
    __builtin_amdgcn_global_load_lds(                                  \
        (const __attribute__((address_space(1))) void*)(g),            \
        (__attribute__((address_space(3))) void*)(l), 16, 0, 0)

#define MFMA32(a, b, c) __builtin_amdgcn_mfma_f32_32x32x16_f16(a, b, c, 0, 0, 0)

#if __has_builtin(__builtin_amdgcn_exp2f)
#define EXP2(x) __builtin_amdgcn_exp2f(x)
#else
static __device__ __forceinline__ float EXP2(float x) {
    float y;
    asm("v_exp_f32 %0, %1" : "=v"(y) : "v"(x));
    return y;
}
#endif

// ---------------- Q: fp32 -> f16 row-major, pre-scaled by log2(e) ----------------
__global__ __launch_bounds__(256) void cvt_kernel(const float* __restrict__ in,
                                                  _Float16* __restrict__ out, int n4) {
    int i = blockIdx.x * 256 + threadIdx.x;
    if (i < n4) {
        float4 v = ((const float4*)in)[i];
        h4 o;
        o.h[0] = (_Float16)(v.x * LOG2E); o.h[1] = (_Float16)(v.y * LOG2E);
        o.h[2] = (_Float16)(v.z * LOG2E); o.h[3] = (_Float16)(v.w * LOG2E);
        ((h4*)out)[i] = o;
    }
}

// ------- K -> Kimg (32x32x16 A-frag order). Granule (s,l) of tile t at
// t*16384 + s*1024 + l*16 holds K[t*32 + (l&31)][s*16 + (l>>5)*8 + j], j=0..7.
// In-kernel QK read for step s = b128 at s*1024 + lane*16: linear, conflict-free.
__global__ __launch_bounds__(256) void cvt_swz_kernel(const float* __restrict__ in,
                                                      _Float16* __restrict__ img,
                                                      int ngran) {
    int id = blockIdx.x * 256 + threadIdx.x;
    if (id >= ngran) return;
    int t = id >> 10, g = id & 1023;
    int s = g >> 6, l = g & 63;
    int row = t * 32 + (l & 31);
    int col = s * 16 + (l >> 5) * 8;
    float4 a = *(const float4*)(in + (size_t)row * D_DIM + col);
    float4 b = *(const float4*)(in + (size_t)row * D_DIM + col + 4);
    f16x8 o;
    o[0] = (_Float16)a.x; o[1] = (_Float16)a.y; o[2] = (_Float16)a.z; o[3] = (_Float16)a.w;
    o[4] = (_Float16)b.x; o[5] = (_Float16)b.y; o[6] = (_Float16)b.z; o[7] = (_Float16)b.w;
    *(f16x8*)((char*)img + (size_t)id * 16) = o;
}

// ------- V -> Vimg (32x32x16 B-frag order, kappa-permuted keys).
// Granule g (dt=g>>7, s=(g>>6)&1, l=g&63) of tile t at t*16384 + g*16 holds
// V[t*32 + kappa(s, l>>5, j)][dt*32 + (l&31)], kappa(s,hi,j)=16s+4hi+8(j>>2)+(j&3).
// kappa matches the cvt_pkrtz pack order of the S^T C-layout -> PV needs NO shuffles.
__global__ __launch_bounds__(256) void vt_swz_kernel(const float* __restrict__ V,
                                                     _Float16* __restrict__ Vimg) {
    __shared__ float tile[32][260];
    const int t = blockIdx.x;
#pragma unroll
    for (int i = 0; i < 8; ++i) {
        int idx = i * 256 + threadIdx.x;
        int kr = idx >> 6, c4 = idx & 63;
        float4 v = *(const float4*)(V + ((size_t)t * 32 + kr) * D_DIM + c4 * 4);
        tile[kr][c4 * 4 + 0] = v.x;
        tile[kr][c4 * 4 + 1] = v.y;
        tile[kr][c4 * 4 + 2] = v.z;
        tile[kr][c4 * 4 + 3] = v.w;
    }
    __syncthreads();
#pragma unroll
    for (int i = 0; i < 4; ++i) {
        int g = i * 256 + threadIdx.x;  // 1024 granules
        int dt = g >> 7, s = (g >> 6) & 1, l = g & 63;
        int hi = l >> 5, d = dt * 32 + (l & 31);
        f16x8 o;
#pragma unroll
        for (int j = 0; j < 8; ++j)
            o[j] = (_Float16)tile[16 * s + 4 * hi + 8 * (j >> 2) + (j & 3)][d];
        *(f16x8*)((char*)Vimg + (size_t)t * VTILE_BYTES + (size_t)g * 16) = o;
    }
}

// ---- flash attention: 32x32x16, q_w=64 (M_rep=2) -> 64 FLOP per LDS byte ----
// 4 waves x 64 q-rows, 1 block/CU (grid 256), 1 wave/SIMD (launch_bounds(256,1):
// acc 256 + qf 128 regs). Each K-granule read feeds BOTH mi QK MFMAs; each
// V-read feeds BOTH mi PV MFMAs -> LDS read bytes halved vs R13 (the measured
// dominant pipe: was ~50us of 92). R12 1-barrier dbuf schedule unchanged.
__global__ __launch_bounds__(256, 1) void attn_kernel(
    const _Float16* __restrict__ Qh, const _Float16* __restrict__ Kimg,
    const _Float16* __restrict__ Vimg, _Float16* __restrict__ Opart,
    float* __restrict__ ml) {
    extern __shared__ __align__(16) char smem[];
    char* sK = smem;          // 2 x 16KB
    char* sV = smem + 32768;  // 2 x 16KB
    const int tid = threadIdx.x;
    const int wave = tid >> 6, lane = tid & 63;
    const int q31 = lane & 31, hi = lane >> 5;
    const int bid = blockIdx.x;
    const int qtile = bid >> 3, split = bid & 7;  // XCD = bid % 8 = split
    const int tile0 = split * NKV;
    const int rot = (qtile & 3) << 2;  // stagger offset (L2 spread)
    const int othr = tid * 16;
    const int lb = lane * 16;

#define TILE_AT(k) (tile0 + (((k) + rot) & (NKV - 1)))
#define STAGE_KV(k, slot)                                                          \
    {                                                                              \
        const char* Kt = (const char*)Kimg + (size_t)TILE_AT(k) * KTILE_BYTES;     \
        const char* Vt = (const char*)Vimg + (size_t)TILE_AT(k) * VTILE_BYTES;     \
        _Pragma("unroll") for (int i = 0; i < 4; ++i) {                            \
            GLOAD_LDS16(Kt + i * 4096 + othr, sK + (slot)*16384 + i * 4096 + othr); \
            GLOAD_LDS16(Vt + i * 4096 + othr, sV + (slot)*16384 + i * 4096 + othr); \
        }                                                                          \
    }

    // ---- Q B-fragments: qf[mi][s] = Q[qrow(mi)][s*16 + hi*8 + j] ----
    f16x8 qf[2][16];
    {
        const size_t qrow0 = (size_t)qtile * QBLK + wave * 64 + q31;
#pragma unroll
        for (int mi = 0; mi < 2; ++mi)
#pragma unroll
            for (int s = 0; s < 16; ++s)
                qf[mi][s] =
                    *(const f16x8*)(Qh + (qrow0 + mi * 32) * D_DIM + s * 16 + hi * 8);
    }

    f32x16 acc[2][8];
#pragma unroll
    for (int mi = 0; mi < 2; ++mi)
#pragma unroll
        for (int dt = 0; dt < 8; ++dt)
#pragma unroll
            for (int r = 0; r < 16; ++r) acc[mi][dt][r] = 0.f;
    float m[2] = {-1e30f, -1e30f};
    float l[2] = {0.f, 0.f};  // per-lane partials (16 of 32 keys), epilogue-reduced

    // ---- prologue: stage tile 0 into slot 0 ----
    STAGE_KV(0, 0);

    for (int kt = 0; kt < NKV; ++kt) {
        asm volatile("s_waitcnt vmcnt(0)" ::: "memory");  // stage(kt) landed (aged)
        __builtin_amdgcn_s_barrier();  // K/V(kt) visible; prior-iter reads done

        if (kt + 1 < NKV) STAGE_KV(kt + 1, (kt + 1) & 1);

        const char* sKb = sK + (kt & 1) * 16384;
        const char* sVb = sV + (kt & 1) * 16384;

        // ---- QK^T swapped: st[mi] = S^T[key=(r&3)+8(r>>2)+4hi][q=mi*32+q31] ----
        f32x16 st[2];
#pragma unroll
        for (int r = 0; r < 16; ++r) { st[0][r] = 0.f; st[1][r] = 0.f; }
#pragma unroll
        for (int s = 0; s < 16; ++s) {
            f16x8 kf = *(const f16x8*)(sKb + s * 1024 + lb);
            st[0] = MFMA32(kf, qf[0][s], st[0]);
            st[1] = MFMA32(kf, qf[1][s], st[1]);
        }

        // ---- online softmax (base-2) + pack; cvt_pk order == kappa order ----
        union PU { unsigned int u[4]; f16x8 v; };
        PU pa[2][2];
#pragma unroll
        for (int mi = 0; mi < 2; ++mi) {
            float pm = st[mi][0];
#pragma unroll
            for (int r = 1; r < 16; ++r) pm = fmaxf(pm, st[mi][r]);
            pm = fmaxf(pm, __shfl_xor(pm, 32));
            if (__any(pm > m[mi] + RESCALE_THR)) {
                float mn = fmaxf(m[mi], pm);
                float sc = EXP2(m[mi] - mn);
                m[mi] = mn;
                l[mi] *= sc;
                float fr[16];
#pragma unroll
                for (int r = 0; r < 16; ++r)
                    fr[r] = __shfl(sc, ((r & 3) + 8 * (r >> 2) + 4 * hi) + 32 * hi - 32 * hi);
#pragma unroll
                for (int r = 0; r < 16; ++r)
                    fr[r] = __shfl(sc, (r & 3) + 8 * (r >> 2) + 4 * hi);
#pragma unroll
                for (int dt = 0; dt < 8; ++dt)
#pragma unroll
                    for (int r = 0; r < 16; ++r) acc[mi][dt][r] *= fr[r];
            }
            float rs = 0.f;
#pragma unroll
            for (int r = 0; r < 16; ++r) {
                float p = EXP2(st[mi][r] - m[mi]);
                st[mi][r] = p;
                rs += p;
            }
            l[mi] += rs;
#pragma unroll
            for (int i = 0; i < 4; ++i) {
                pa[mi][0].u[i] = __builtin_bit_cast(
                    unsigned int,
                    __builtin_amdgcn_cvt_pkrtz(st[mi][2 * i], st[mi][2 * i + 1]));
                pa[mi][1].u[i] = __builtin_bit_cast(
                    unsigned int,
                    __builtin_amdgcn_cvt_pkrtz(st[mi][8 + 2 * i], st[mi][9 + 2 * i]));
            }
        }

        // ---- PV: acc[mi][dt] += P x V (each vf read feeds both mi) ----
#pragma unroll
        for (int dt = 0; dt < 8; ++dt) {
            f16x8 vf0 = *(const f16x8*)(sVb + dt * 2048 + lb);
            f16x8 vf1 = *(const f16x8*)(sVb + dt * 2048 + 1024 + lb);
            acc[0][dt] = MFMA32(pa[0][0].v, vf0, acc[0][dt]);
            acc[1][dt] = MFMA32(pa[1][0].v, vf0, acc[1][dt]);
            acc[0][dt] = MFMA32(pa[0][1].v, vf1, acc[0][dt]);
            acc[1][dt] = MFMA32(pa[1][1].v, vf1, acc[1][dt]);
        }
    }

    // ---- epilogue: unnormalized partial O (f16) + (m,l) ----
    _Float16* Ob = Opart + (size_t)(qtile * TSPLIT + split) * QBLK * D_DIM;
#pragma unroll
    for (int mi = 0; mi < 2; ++mi)
#pragma unroll
        for (int dt = 0; dt < 8; ++dt)
#pragma unroll
            for (int r = 0; r < 16; ++r) {
                int q = (r & 3) + 8 * (r >> 2) + 4 * hi;
                int row = wave * 64 + mi * 32 + q;
                int col = dt * 32 + q31;
                Ob[(size_t)row * D_DIM + col] = (_Float16)acc[mi][dt][r];
            }
#pragma unroll
    for (int mi = 0; mi < 2; ++mi) l[mi] += __shfl_xor(l[mi], 32);
    if (lane < 32) {
        float* mlb = ml + (size_t)((qtile * TSPLIT + split) * QBLK) * 2;
#pragma unroll
        for (int mi = 0; mi < 2; ++mi) {
            int row = wave * 64 + mi * 32 + lane;
            mlb[row * 2 + 0] = m[mi];
            mlb[row * 2 + 1] = l[mi];
        }
    }
}

// ---------------- combine TSPLIT partials (base-2 stats) ----------------
__global__ __launch_bounds__(256) void combine_kernel(const _Float16* __restrict__ Opart,
                                                      const float* __restrict__ ml,
                                                      float* __restrict__ out) {
    int r = blockIdx.x;
    int qtile = r >> 8, rl = r & 255;  // QBLK=256
    int d = threadIdx.x;
    float mv[TSPLIT], lv[TSPLIT];
    float M = -1e30f;
#pragma unroll
    for (int s = 0; s < TSPLIT; ++s) {
        const float* mlb = ml + (size_t)((qtile * TSPLIT + s) * QBLK + rl) * 2;
        mv[s] = mlb[0];
        lv[s] = mlb[1];
        M = fmaxf(M, mv[s]);
    }
    float num = 0.f, den = 0.f;
#pragma unroll
    for (int s = 0; s < TSPLIT; ++s) {
        float w = EXP2(mv[s] - M);
        num += w * (float)Opart[((size_t)(qtile * TSPLIT + s) * QBLK + rl) * D_DIM + d];
        den += w * lv[s];
    }
    out[(size_t)r * D_DIM + d] = num / den;
}

extern "C" void kernel_launch(void* const* d_in, const int* in_sizes, int n_in,
                              void* d_out, int out_size, void* d_ws, size_t ws_size,
                              hipStream_t stream) {
    const float* Q = (const float*)d_in[0];
    const float* K = (const float*)d_in[1];
    const float* V = (const float*)d_in[2];
    float* out = (float*)d_out;
    char* ws = (char*)d_ws;

    _Float16* Qh = (_Float16*)ws;                    // 4MB row-major f16 (x log2e)
    _Float16* Kimg = (_Float16*)(ws + (4 << 20));    // 4MB 32x32 A-frag tiles
    _Float16* Vimg = (_Float16*)(ws + (8 << 20));    // 4MB 32x32 B-frag tiles (kappa)
    _Float16* Opart = (_Float16*)(ws + (12 << 20));  // 32MB f16 partials
    float* ml = (float*)(ws + ((size_t)44 << 20));   // 512KB

    const int n4 = S_LEN * D_DIM / 4;
    const int ngran = S_LEN * D_DIM / 8;  // 262144 granules
    cvt_kernel<<<n4 / 256, 256, 0, stream>>>(Q, Qh, n4);
    cvt_swz_kernel<<<ngran / 256, 256, 0, stream>>>(K, Kimg, ngran);
    vt_swz_kernel<<<T_LEN / 32, 256, 0, stream>>>(V, Vimg);

    // 256 blocks x 256 thr, 64KB dyn LDS -> 1 block/CU; bid&7 = split = XCD id
    attn_kernel<<<NQT * TSPLIT, 256, SMEM_BYTES, stream>>>(Qh, Kimg, Vimg, Opart, ml);
    combine_kernel<<<S_LEN, 256, 0, stream>>>(Opart, ml, out);
}

// Round 15
// 207.682 us; speedup vs baseline: 2.6736x; 2.6736x over previous
//
#include <hip/hip_runtime.h>
#include <hip/hip_fp16.h>

#define S_LEN 8192
#define T_LEN 8192
#define D_DIM 256
#define QBLK 128
#define KVBLK 32
#define TSPLIT 8
#define NKV ((T_LEN / TSPLIT) / KVBLK)  // 32 tiles per block
#define NQT (S_LEN / QBLK)              // 64
#define KTILE_BYTES 16384               // 32 keys x 256 d x 2B (linear-read image)
#define VTILE_BYTES 16384               // 256 d x 32 keys x 2B (linear-read image)
#define RESCALE_THR 6.0f                // log2 domain
#define LOG2E 1.44269504f
// LDS: Kb 2x16KB only (V goes global->register) -> 32768 B
#define SMEM_BYTES 32768

typedef _Float16 f16x8 __attribute__((ext_vector_type(8)));
typedef float f32x4 __attribute__((ext_vector_type(4)));

struct h4 { _Float16 h[4]; };

#define GLOAD_LDS16(g, l)                                              \
    __builtin_amdgcn_global_load_lds(                                  \
        (const __attribute__((address_space(1))) void*)(g),            \
        (__attribute__((address_space(3))) void*)(l), 16, 0, 0)

#define MFMA16(a, b, c) __builtin_amdgcn_mfma_f32_16x16x32_f16(a, b, c, 0, 0, 0)

#if __has_builtin(__builtin_amdgcn_exp2f)
#define EXP2(x) __builtin_amdgcn_exp2f(x)
#else
static __device__ __forceinline__ float EXP2(float x) {
    float y;
    asm("v_exp_f32 %0, %1" : "=v"(y) : "v"(x));
    return y;
}
#endif

// ---------------- Q: fp32 -> f16 row-major, pre-scaled by log2(e) ----------------
__global__ __launch_bounds__(256) void cvt_kernel(const float* __restrict__ in,
                                                  _Float16* __restrict__ out, int n4) {
    int i = blockIdx.x * 256 + threadIdx.x;
    if (i < n4) {
        float4 v = ((const float4*)in)[i];
        h4 o;
        o.h[0] = (_Float16)(v.x * LOG2E); o.h[1] = (_Float16)(v.y * LOG2E);
        o.h[2] = (_Float16)(v.z * LOG2E); o.h[3] = (_Float16)(v.w * LOG2E);
        ((h4*)out)[i] = o;
    }
}

// ------- K -> Kimg. Granule (row r, gr) of tile t (gr = dim/8, ks=gr>>2, g=gr&3)
// placed at ks*2048 + (r>>4)*1024 + (r&15)*64 + g*16  -> the QK read of step
// (ks, half) is a CONTIGUOUS 1KB wave-read (conflict-free, zero swizzle VALU).
__global__ __launch_bounds__(256) void cvt_swz_kernel(const float* __restrict__ in,
                                                      _Float16* __restrict__ img,
                                                      int nchunks) {
    int id = blockIdx.x * 256 + threadIdx.x;
    if (id >= nchunks) return;
    int row = id >> 5, gr = id & 31;
    int t = row >> 5, r = row & 31;
    float4 a = *(const float4*)(in + (size_t)row * D_DIM + gr * 8);
    float4 b = *(const float4*)(in + (size_t)row * D_DIM + gr * 8 + 4);
    f16x8 o;
    o[0] = (_Float16)a.x; o[1] = (_Float16)a.y; o[2] = (_Float16)a.z; o[3] = (_Float16)a.w;
    o[4] = (_Float16)b.x; o[5] = (_Float16)b.y; o[6] = (_Float16)b.z; o[7] = (_Float16)b.w;
    *(f16x8*)((char*)img + (size_t)t * KTILE_BYTES + (gr >> 2) * 2048 +
              ((r >> 4) << 10) + ((r & 15) << 6) + ((gr & 3) << 4)) = o;
}

// ------- V -> Vimg. Granule (d, gk) holds keys pi(gk*8+j)=(j>>2)*16+gk*4+(j&3),
// at (d>>4)*1024 + gk*256 + (d&15)*16 -> PV read addr = dt*1024 + lane*16
// (read DIRECTLY from global: coalesced 1KB wave-reads, L2/L1-resident). -------
__global__ __launch_bounds__(256) void vt_swz_kernel(const float* __restrict__ V,
                                                     _Float16* __restrict__ Vimg) {
    __shared__ float tile[32][260];
    const int t = blockIdx.x;
#pragma unroll
    for (int i = 0; i < 8; ++i) {
        int idx = i * 256 + threadIdx.x;
        int kr = idx >> 6, c4 = idx & 63;
        float4 v = *(const float4*)(V + ((size_t)t * 32 + kr) * D_DIM + c4 * 4);
        tile[kr][c4 * 4 + 0] = v.x;
        tile[kr][c4 * 4 + 1] = v.y;
        tile[kr][c4 * 4 + 2] = v.z;
        tile[kr][c4 * 4 + 3] = v.w;
    }
    __syncthreads();
#pragma unroll
    for (int i = 0; i < 4; ++i) {
        int gid = i * 256 + threadIdx.x;
        int d = gid >> 2, gk = gid & 3;
        f16x8 o;
#pragma unroll
        for (int j = 0; j < 8; ++j)
            o[j] = (_Float16)tile[(j >> 2) * 16 + gk * 4 + (j & 3)][d];
        *(f16x8*)((char*)Vimg + (size_t)t * VTILE_BYTES + ((d >> 4) << 10) +
                  (gk << 8) + ((d & 15) << 4)) = o;
    }
}

// ------------- flash attention: R12 base + V direct global->register -------------
// 4 waves x 32 q-rows (M_rep=2). K double-buffered in LDS (32KB); V tile read
// straight from Vimg (global, L2/L1-resident) into 64 VGPRs per tile -- removes
// ~45% of LDS read traffic + all V staging writes; V loads fly under QK+softmax
// on the vector-memory pipe. Schedule: {lgkmcnt0; vmcnt0; barrier} -> V(kt)->reg
// -> stage K(kt+1) -> QK -> softmax -> PV (compiler waits vmcnt(4): K-stage only).
__global__ __launch_bounds__(256, 2) void attn_kernel(
    const _Float16* __restrict__ Qh, const _Float16* __restrict__ Kimg,
    const _Float16* __restrict__ Vimg, _Float16* __restrict__ Opart,
    float* __restrict__ ml) {
    extern __shared__ __align__(16) char smem[];
    char* sK = smem;  // 2 x 16KB
    const int tid = threadIdx.x;
    const int wave = tid >> 6, lane = tid & 63;
    const int g = lane >> 4, c = lane & 15;
    const int bid = blockIdx.x;
    const int qtile = bid >> 3, split = bid & 7;  // XCD = bid % 8 = split
    const int tile0 = split * NKV;
    const int rot = ((qtile >> 5) << 4) | ((qtile & 3) << 2);  // stagger offset
    const int othr = tid * 16;
    const int kbase = ((lane & 15) << 6) | ((lane >> 4) << 4);  // c*64 + g*16
    const int vbase = lane << 4;

#define TILE_AT(k) (tile0 + (((k) + rot) & (NKV - 1)))
#define STAGE_K(k, slot)                                                            \
    {                                                                               \
        const char* Kt = (const char*)Kimg + (size_t)TILE_AT(k) * KTILE_BYTES;      \
        _Pragma("unroll") for (int i = 0; i < 4; ++i) {                             \
            GLOAD_LDS16(Kt + i * 4096 + othr, sK + (slot)*16384 + i * 4096 + othr); \
        }                                                                           \
    }

    // ---- Q B-fragments: B[n=q=c][k = ks*32 + g*8 + j] ----
    f16x8 qf[2][8];
    {
        const size_t qrow0 = (size_t)qtile * QBLK + wave * 32 + c;
#pragma unroll
        for (int mi = 0; mi < 2; ++mi)
#pragma unroll
            for (int ks = 0; ks < 8; ++ks)
                qf[mi][ks] =
                    *(const f16x8*)(Qh + (qrow0 + mi * 16) * D_DIM + (ks * 4 + g) * 8);
    }

    f32x4 acc[2][16];
#pragma unroll
    for (int mi = 0; mi < 2; ++mi)
#pragma unroll
        for (int dt = 0; dt < 16; ++dt) acc[mi][dt] = (f32x4){0.f, 0.f, 0.f, 0.f};
    float m[2] = {-1e30f, -1e30f};
    float l[2] = {0.f, 0.f};  // per-lane partials, reduced at epilogue

    // ---- prologue: stage K tile 0 into slot 0 ----
    STAGE_K(0, 0);

    for (int kt = 0; kt < NKV; ++kt) {
        asm volatile("s_waitcnt lgkmcnt(0)" ::: "memory");
        asm volatile("s_waitcnt vmcnt(0)" ::: "memory");  // K-stage(kt) landed (aged)
        __builtin_amdgcn_s_barrier();  // K(kt) visible; prior-iter slot reads done

        // ---- issue V(kt) global->reg: flies under QK + softmax ----
        f16x8 vf[16];
        {
            const char* Vg = (const char*)Vimg + (size_t)TILE_AT(kt) * VTILE_BYTES;
#pragma unroll
            for (int dt = 0; dt < 16; ++dt)
                vf[dt] = *(const f16x8*)(Vg + dt * 1024 + vbase);
        }

        // stage K(kt+1) into the opposite slot: flies under compute(kt)
        if (kt + 1 < NKV) STAGE_K(kt + 1, (kt + 1) & 1);

        const char* sKb = sK + (kt & 1) * 16384;

        // ---- QK^T swapped: st[mi][ct] = S^T[key=ct*16+g*4+r][q=mi*16+c] ----
        f32x4 st[2][2];
#pragma unroll
        for (int mi = 0; mi < 2; ++mi)
#pragma unroll
            for (int ct = 0; ct < 2; ++ct) st[mi][ct] = (f32x4){0.f, 0.f, 0.f, 0.f};
        __builtin_amdgcn_s_setprio(1);
#pragma unroll
        for (int ks = 0; ks < 8; ++ks) {
            f16x8 kf0 = *(const f16x8*)(sKb + ks * 2048 + kbase);
            f16x8 kf1 = *(const f16x8*)(sKb + ks * 2048 + 1024 + kbase);
            st[0][0] = MFMA16(kf0, qf[0][ks], st[0][0]);
            st[0][1] = MFMA16(kf1, qf[0][ks], st[0][1]);
            st[1][0] = MFMA16(kf0, qf[1][ks], st[1][0]);
            st[1][1] = MFMA16(kf1, qf[1][ks], st[1][1]);
        }
        __builtin_amdgcn_s_setprio(0);

        // ---- online softmax, base-2 (q-row = c; keys spread over g,ct,r) ----
        union PU { unsigned int u[4]; f16x8 v; };
        PU pu[2];
#pragma unroll
        for (int mi = 0; mi < 2; ++mi) {
            float pm = fmaxf(fmaxf(fmaxf(st[mi][0][0], st[mi][0][1]),
                                   fmaxf(st[mi][0][2], st[mi][0][3])),
                             fmaxf(fmaxf(st[mi][1][0], st[mi][1][1]),
                                   fmaxf(st[mi][1][2], st[mi][1][3])));
            if (__any(pm > m[mi] + RESCALE_THR)) {
                pm = fmaxf(pm, __shfl_xor(pm, 16));
                pm = fmaxf(pm, __shfl_xor(pm, 32));
                float mn = fmaxf(m[mi], pm);
                float sc = EXP2(m[mi] - mn);
                m[mi] = mn;
                l[mi] *= sc;
                float fr[4];
#pragma unroll
                for (int r = 0; r < 4; ++r) fr[r] = __shfl(sc, (g << 4) | (g * 4 + r));
#pragma unroll
                for (int dt = 0; dt < 16; ++dt)
#pragma unroll
                    for (int r = 0; r < 4; ++r) acc[mi][dt][r] *= fr[r];
            }
            float rs = 0.f;
#pragma unroll
            for (int ct = 0; ct < 2; ++ct)
#pragma unroll
                for (int r = 0; r < 4; ++r) {
                    float p = EXP2(st[mi][ct][r] - m[mi]);
                    st[mi][ct][r] = p;
                    rs += p;
                }
            l[mi] += rs;  // per-lane partial; reduced at epilogue
            // pack P in-lane: A'[q=c][kslot g*8+j], pi(g*8+j)=(j>>2)*16+g*4+(j&3)
            pu[mi].u[0] = __builtin_bit_cast(
                unsigned int, __builtin_amdgcn_cvt_pkrtz(st[mi][0][0], st[mi][0][1]));
            pu[mi].u[1] = __builtin_bit_cast(
                unsigned int, __builtin_amdgcn_cvt_pkrtz(st[mi][0][2], st[mi][0][3]));
            pu[mi].u[2] = __builtin_bit_cast(
                unsigned int, __builtin_amdgcn_cvt_pkrtz(st[mi][1][0], st[mi][1][1]));
            pu[mi].u[3] = __builtin_bit_cast(
                unsigned int, __builtin_amdgcn_cvt_pkrtz(st[mi][1][2], st[mi][1][3]));
        }

        // ---- PV(kt): acc += P' x V' (V in registers; zero LDS traffic) ----
        __builtin_amdgcn_s_setprio(1);
#pragma unroll
        for (int dt = 0; dt < 16; ++dt) {
            acc[0][dt] = MFMA16(pu[0].v, vf[dt], acc[0][dt]);
            acc[1][dt] = MFMA16(pu[1].v, vf[dt], acc[1][dt]);
        }
        __builtin_amdgcn_s_setprio(0);
    }

    // ---- epilogue: unnormalized partial O (f16) + (m,l) ----
    _Float16* Ob = Opart + (size_t)(qtile * TSPLIT + split) * QBLK * D_DIM;
#pragma unroll
    for (int mi = 0; mi < 2; ++mi)
#pragma unroll
        for (int dt = 0; dt < 16; ++dt)
#pragma unroll
            for (int r = 0; r < 4; ++r) {
                int row = wave * 32 + mi * 16 + g * 4 + r;
                int col = dt * 16 + c;
                Ob[(size_t)row * D_DIM + col] = (_Float16)acc[mi][dt][r];
            }
#pragma unroll
    for (int mi = 0; mi < 2; ++mi) {
        l[mi] += __shfl_xor(l[mi], 16);
        l[mi] += __shfl_xor(l[mi], 32);
    }
    if (g == 0) {
        float* mlb = ml + (size_t)((qtile * TSPLIT + split) * QBLK) * 2;
#pragma unroll
        for (int mi = 0; mi < 2; ++mi) {
            int row = wave * 32 + mi * 16 + c;
            mlb[row * 2 + 0] = m[mi];
            mlb[row * 2 + 1] = l[mi];
        }
    }
}

// ---------------- combine TSPLIT partials (base-2 stats) ----------------
__global__ __launch_bounds__(256) void combine_kernel(const _Float16* __restrict__ Opart,
                                                      const float* __restrict__ ml,
                                                      float* __restrict__ out) {
    int r = blockIdx.x;
    int qtile = r >> 7, rl = r & 127;  // QBLK=128
    int d = threadIdx.x;
    float mv[TSPLIT], lv[TSPLIT];
    float M = -1e30f;
#pragma unroll
    for (int s = 0; s < TSPLIT; ++s) {
        const float* mlb = ml + (size_t)((qtile * TSPLIT + s) * QBLK + rl) * 2;
        mv[s] = mlb[0];
        lv[s] = mlb[1];
        M = fmaxf(M, mv[s]);
    }
    float num = 0.f, den = 0.f;
#pragma unroll
    for (int s = 0; s < TSPLIT; ++s) {
        float w = EXP2(mv[s] - M);
        num += w * (float)Opart[((size_t)(qtile * TSPLIT + s) * QBLK + rl) * D_DIM + d];
        den += w * lv[s];
    }
    out[(size_t)r * D_DIM + d] = num / den;
}

extern "C" void kernel_launch(void* const* d_in, const int* in_sizes, int n_in,
                              void* d_out, int out_size, void* d_ws, size_t ws_size,
                              hipStream_t stream) {
    const float* Q = (const float*)d_in[0];
    const float* K = (const float*)d_in[1];
    const float* V = (const float*)d_in[2];
    float* out = (float*)d_out;
    char* ws = (char*)d_ws;

    _Float16* Qh = (_Float16*)ws;                    // 4MB row-major f16 (x log2e)
    _Float16* Kimg = (_Float16*)(ws + (4 << 20));    // 4MB linear-read 32-key tiles
    _Float16* Vimg = (_Float16*)(ws + (8 << 20));    // 4MB linear-read transposed tiles
    _Float16* Opart = (_Float16*)(ws + (12 << 20));  // 32MB f16 partials
    float* ml = (float*)(ws + ((size_t)44 << 20));   // 512KB

    const int n4 = S_LEN * D_DIM / 4;
    const int nchunks = S_LEN * D_DIM / 8;
    cvt_kernel<<<n4 / 256, 256, 0, stream>>>(Q, Qh, n4);
    cvt_swz_kernel<<<nchunks / 256, 256, 0, stream>>>(K, Kimg, nchunks);
    vt_swz_kernel<<<T_LEN / 32, 256, 0, stream>>>(V, Vimg);

    // 512 blocks x 256 thr, 32KB dyn LDS -> 2 blocks/CU; bid&7 = split = XCD id
    attn_kernel<<<NQT * TSPLIT, 256, SMEM_BYTES, stream>>>(Qh, Kimg, Vimg, Opart, ml);
    combine_kernel<<<S_LEN, 256, 0, stream>>>(Opart, ml, out);
}

// Round 16
// 99.750 us; speedup vs baseline: 5.5664x; 2.0820x over previous
//
#include <hip/hip_runtime.h>
#include <hip/hip_fp16.h>

#define S_LEN 8192
#define T_LEN 8192
#define D_DIM 256
#define QBLK 128
#define KVBLK 32
#define TSPLIT 8
#define NKV ((T_LEN / TSPLIT) / KVBLK)  // 32 tiles per block
#define NQT (S_LEN / QBLK)              // 64
#define KTILE_BYTES 16384               // 32 keys x 256 d x 2B (linear-read image)
#define VTILE_BYTES 16384               // 256 d x 32 keys x 2B (linear-read image)
#define RESCALE_THR 6.0f                // log2 domain
#define LOG2E 1.44269504f
// LDS: Kb 2x16KB @0 ; Vb 2x16KB @32768 -> 65536 B -> 2 blocks/CU
#define SMEM_BYTES 65536

typedef _Float16 f16x8 __attribute__((ext_vector_type(8)));
typedef float f32x4 __attribute__((ext_vector_type(4)));

struct h4 { _Float16 h[4]; };

#define GLOAD_LDS16(g, l)                                              \
    __builtin_amdgcn_global_load_lds(                                  \
        (const __attribute__((address_space(1))) void*)(g),            \
        (__attribute__((address_space(3))) void*)(l), 16, 0, 0)

#define MFMA16(a, b, c) __builtin_amdgcn_mfma_f32_16x16x32_f16(a, b, c, 0, 0, 0)

#if __has_builtin(__builtin_amdgcn_exp2f)
#define EXP2(x) __builtin_amdgcn_exp2f(x)
#else
static __device__ __forceinline__ float EXP2(float x) {
    float y;
    asm("v_exp_f32 %0, %1" : "=v"(y) : "v"(x));
    return y;
}
#endif

// ------------- fused producer: Q cvt | K swz-image | V transpose-image -------------
// grid = 1024 (Q) + 1024 (K) + 256 (V) = 2304 blocks x 256 threads.
//  Q: fp32 -> f16 row-major, pre-scaled by log2(e).
//  K image: granule (row r, gr) of tile t (ks=gr>>2, g=gr&3) at
//    t*16384 + ks*2048 + (r>>4)*1024 + (r&15)*64 + g*16 -> QK step (ks,half)
//    reads are CONTIGUOUS 1KB wave-reads (conflict-free, zero swizzle VALU).
//  V image: granule (d, gk) holds keys pi(gk*8+j)=(j>>2)*16+gk*4+(j&3), at
//    (d>>4)*1024 + gk*256 + (d&15)*16 -> PV read addr = dt*1024 + lane*16.
__global__ __launch_bounds__(256) void producer_kernel(
    const float* __restrict__ Q, const float* __restrict__ K,
    const float* __restrict__ V, _Float16* __restrict__ Qh,
    _Float16* __restrict__ Kimg, _Float16* __restrict__ Vimg) {
    __shared__ float tile[32][260];
    const int bid = blockIdx.x;
    const int tidx = threadIdx.x;

    if (bid < 1024) {
        // ---- Q convert: 512 float4 per block ----
#pragma unroll
        for (int it = 0; it < 2; ++it) {
            int i = bid * 512 + it * 256 + tidx;
            float4 v = ((const float4*)Q)[i];
            h4 o;
            o.h[0] = (_Float16)(v.x * LOG2E); o.h[1] = (_Float16)(v.y * LOG2E);
            o.h[2] = (_Float16)(v.z * LOG2E); o.h[3] = (_Float16)(v.w * LOG2E);
            ((h4*)Qh)[i] = o;
        }
    } else if (bid < 2048) {
        // ---- K swizzle image: 256 granules per block ----
        int id = (bid - 1024) * 256 + tidx;
        int row = id >> 5, gr = id & 31;
        int t = row >> 5, r = row & 31;
        float4 a = *(const float4*)(K + (size_t)row * D_DIM + gr * 8);
        float4 b = *(const float4*)(K + (size_t)row * D_DIM + gr * 8 + 4);
        f16x8 o;
        o[0] = (_Float16)a.x; o[1] = (_Float16)a.y;
        o[2] = (_Float16)a.z; o[3] = (_Float16)a.w;
        o[4] = (_Float16)b.x; o[5] = (_Float16)b.y;
        o[6] = (_Float16)b.z; o[7] = (_Float16)b.w;
        *(f16x8*)((char*)Kimg + (size_t)t * KTILE_BYTES + (gr >> 2) * 2048 +
                  ((r >> 4) << 10) + ((r & 15) << 6) + ((gr & 3) << 4)) = o;
    } else {
        // ---- V transpose image: one 32-key tile per block ----
        const int t = bid - 2048;
#pragma unroll
        for (int i = 0; i < 8; ++i) {
            int idx = i * 256 + tidx;
            int kr = idx >> 6, c4 = idx & 63;
            float4 v = *(const float4*)(V + ((size_t)t * 32 + kr) * D_DIM + c4 * 4);
            tile[kr][c4 * 4 + 0] = v.x;
            tile[kr][c4 * 4 + 1] = v.y;
            tile[kr][c4 * 4 + 2] = v.z;
            tile[kr][c4 * 4 + 3] = v.w;
        }
        __syncthreads();
#pragma unroll
        for (int i = 0; i < 4; ++i) {
            int gid = i * 256 + tidx;
            int d = gid >> 2, gk = gid & 3;
            f16x8 o;
#pragma unroll
            for (int j = 0; j < 8; ++j)
                o[j] = (_Float16)tile[(j >> 2) * 16 + gk * 4 + (j & 3)][d];
            *(f16x8*)((char*)Vimg + (size_t)t * VTILE_BYTES + ((d >> 4) << 10) +
                      (gk << 8) + ((d & 15) << 4)) = o;
        }
    }
}

// ------------- flash attention: R12 champion, verbatim -------------
// 4 waves x 32 q-rows (M_rep=2), dbuf K+V (64KB), 2 blocks/CU.
// Per tile: {lgkmcnt(0); vmcnt(0); barrier} -> stage(kt+1) into slot (kt+1)&1
// -> QK(kt) -> softmax -> PV(kt). Register ledger: 124 arch VGPR + 128 acc =
// within 4 of the (256,2) cap -> NO variant may add register state (R14/R15).
__global__ __launch_bounds__(256, 2) void attn_kernel(
    const _Float16* __restrict__ Qh, const _Float16* __restrict__ Kimg,
    const _Float16* __restrict__ Vimg, _Float16* __restrict__ Opart,
    float* __restrict__ ml) {
    extern __shared__ __align__(16) char smem[];
    char* sK = smem;          // 2 x 16KB
    char* sV = smem + 32768;  // 2 x 16KB
    const int tid = threadIdx.x;
    const int wave = tid >> 6, lane = tid & 63;
    const int g = lane >> 4, c = lane & 15;
    const int bid = blockIdx.x;
    const int qtile = bid >> 3, split = bid & 7;  // XCD = bid % 8 = split
    const int tile0 = split * NKV;
    const int rot = ((qtile >> 5) << 4) | ((qtile & 3) << 2);  // stagger offset
    const int othr = tid * 16;
    const int kbase = ((lane & 15) << 6) | ((lane >> 4) << 4);  // c*64 + g*16
    const int vbase = lane << 4;

#define TILE_AT(k) (tile0 + (((k) + rot) & (NKV - 1)))
#define STAGE_KV(k, slot)                                                          \
    {                                                                              \
        const char* Kt = (const char*)Kimg + (size_t)TILE_AT(k) * KTILE_BYTES;     \
        const char* Vt = (const char*)Vimg + (size_t)TILE_AT(k) * VTILE_BYTES;     \
        _Pragma("unroll") for (int i = 0; i < 4; ++i) {                            \
            GLOAD_LDS16(Kt + i * 4096 + othr, sK + (slot)*16384 + i * 4096 + othr); \
            GLOAD_LDS16(Vt + i * 4096 + othr, sV + (slot)*16384 + i * 4096 + othr); \
        }                                                                          \
    }

    // ---- Q B-fragments: B[n=q=c][k = ks*32 + g*8 + j] ----
    f16x8 qf[2][8];
    {
        const size_t qrow0 = (size_t)qtile * QBLK + wave * 32 + c;
#pragma unroll
        for (int mi = 0; mi < 2; ++mi)
#pragma unroll
            for (int ks = 0; ks < 8; ++ks)
                qf[mi][ks] =
                    *(const f16x8*)(Qh + (qrow0 + mi * 16) * D_DIM + (ks * 4 + g) * 8);
    }

    f32x4 acc[2][16];
#pragma unroll
    for (int mi = 0; mi < 2; ++mi)
#pragma unroll
        for (int dt = 0; dt < 16; ++dt) acc[mi][dt] = (f32x4){0.f, 0.f, 0.f, 0.f};
    float m[2] = {-1e30f, -1e30f};
    float l[2] = {0.f, 0.f};  // per-lane partials, reduced at epilogue

    // ---- prologue: stage tile 0 into slot 0 ----
    STAGE_KV(0, 0);

    for (int kt = 0; kt < NKV; ++kt) {
        asm volatile("s_waitcnt lgkmcnt(0)" ::: "memory");
        asm volatile("s_waitcnt vmcnt(0)" ::: "memory");  // stage(kt) landed (aged)
        __builtin_amdgcn_s_barrier();  // K/V(kt) visible; all prior-iter reads done

        // stage(kt+1) into the opposite slot: flies under compute(kt)
        if (kt + 1 < NKV) STAGE_KV(kt + 1, (kt + 1) & 1);

        const char* sKb = sK + (kt & 1) * 16384;
        const char* sVb = sV + (kt & 1) * 16384;

        // ---- QK^T swapped: st[mi][ct] = S^T[key=ct*16+g*4+r][q=mi*16+c] ----
        f32x4 st[2][2];
#pragma unroll
        for (int mi = 0; mi < 2; ++mi)
#pragma unroll
            for (int ct = 0; ct < 2; ++ct) st[mi][ct] = (f32x4){0.f, 0.f, 0.f, 0.f};
        __builtin_amdgcn_s_setprio(1);
#pragma unroll
        for (int ks = 0; ks < 8; ++ks) {
            f16x8 kf0 = *(const f16x8*)(sKb + ks * 2048 + kbase);
            f16x8 kf1 = *(const f16x8*)(sKb + ks * 2048 + 1024 + kbase);
            st[0][0] = MFMA16(kf0, qf[0][ks], st[0][0]);
            st[0][1] = MFMA16(kf1, qf[0][ks], st[0][1]);
            st[1][0] = MFMA16(kf0, qf[1][ks], st[1][0]);
            st[1][1] = MFMA16(kf1, qf[1][ks], st[1][1]);
        }
        __builtin_amdgcn_s_setprio(0);

        // ---- online softmax, base-2 (q-row = c; keys spread over g,ct,r) ----
        union PU { unsigned int u[4]; f16x8 v; };
        PU pu[2];
#pragma unroll
        for (int mi = 0; mi < 2; ++mi) {
            float pm = fmaxf(fmaxf(fmaxf(st[mi][0][0], st[mi][0][1]),
                                   fmaxf(st[mi][0][2], st[mi][0][3])),
                             fmaxf(fmaxf(st[mi][1][0], st[mi][1][1]),
                                   fmaxf(st[mi][1][2], st[mi][1][3])));
            if (__any(pm > m[mi] + RESCALE_THR)) {
                pm = fmaxf(pm, __shfl_xor(pm, 16));
                pm = fmaxf(pm, __shfl_xor(pm, 32));
                float mn = fmaxf(m[mi], pm);
                float sc = EXP2(m[mi] - mn);
                m[mi] = mn;
                l[mi] *= sc;
                float fr[4];
#pragma unroll
                for (int r = 0; r < 4; ++r) fr[r] = __shfl(sc, (g << 4) | (g * 4 + r));
#pragma unroll
                for (int dt = 0; dt < 16; ++dt)
#pragma unroll
                    for (int r = 0; r < 4; ++r) acc[mi][dt][r] *= fr[r];
            }
            float rs = 0.f;
#pragma unroll
            for (int ct = 0; ct < 2; ++ct)
#pragma unroll
                for (int r = 0; r < 4; ++r) {
                    float p = EXP2(st[mi][ct][r] - m[mi]);
                    st[mi][ct][r] = p;
                    rs += p;
                }
            l[mi] += rs;  // per-lane partial; reduced at epilogue
            // pack P in-lane: A'[q=c][kslot g*8+j], pi(g*8+j)=(j>>2)*16+g*4+(j&3)
            pu[mi].u[0] = __builtin_bit_cast(
                unsigned int, __builtin_amdgcn_cvt_pkrtz(st[mi][0][0], st[mi][0][1]));
            pu[mi].u[1] = __builtin_bit_cast(
                unsigned int, __builtin_amdgcn_cvt_pkrtz(st[mi][0][2], st[mi][0][3]));
            pu[mi].u[2] = __builtin_bit_cast(
                unsigned int, __builtin_amdgcn_cvt_pkrtz(st[mi][1][0], st[mi][1][1]));
            pu[mi].u[3] = __builtin_bit_cast(
                unsigned int, __builtin_amdgcn_cvt_pkrtz(st[mi][1][2], st[mi][1][3]));
        }

        // ---- PV(kt): acc += P' x V'  (fused: one vf read feeds both mi) ----
        __builtin_amdgcn_s_setprio(1);
#pragma unroll
        for (int dt = 0; dt < 16; ++dt) {
            f16x8 vf = *(const f16x8*)(sVb + dt * 1024 + vbase);
            acc[0][dt] = MFMA16(pu[0].v, vf, acc[0][dt]);
            acc[1][dt] = MFMA16(pu[1].v, vf, acc[1][dt]);
        }
        __builtin_amdgcn_s_setprio(0);
    }

    // ---- epilogue: unnormalized partial O (f16) + (m,l) ----
    _Float16* Ob = Opart + (size_t)(qtile * TSPLIT + split) * QBLK * D_DIM;
#pragma unroll
    for (int mi = 0; mi < 2; ++mi)
#pragma unroll
        for (int dt = 0; dt < 16; ++dt)
#pragma unroll
            for (int r = 0; r < 4; ++r) {
                int row = wave * 32 + mi * 16 + g * 4 + r;
                int col = dt * 16 + c;
                Ob[(size_t)row * D_DIM + col] = (_Float16)acc[mi][dt][r];
            }
#pragma unroll
    for (int mi = 0; mi < 2; ++mi) {
        l[mi] += __shfl_xor(l[mi], 16);
        l[mi] += __shfl_xor(l[mi], 32);
    }
    if (g == 0) {
        float* mlb = ml + (size_t)((qtile * TSPLIT + split) * QBLK) * 2;
#pragma unroll
        for (int mi = 0; mi < 2; ++mi) {
            int row = wave * 32 + mi * 16 + c;
            mlb[row * 2 + 0] = m[mi];
            mlb[row * 2 + 1] = l[mi];
        }
    }
}

// ---------------- combine TSPLIT partials (base-2 stats) ----------------
__global__ __launch_bounds__(256) void combine_kernel(const _Float16* __restrict__ Opart,
                                                      const float* __restrict__ ml,
                                                      float* __restrict__ out) {
    int r = blockIdx.x;
    int qtile = r >> 7, rl = r & 127;  // QBLK=128
    int d = threadIdx.x;
    float mv[TSPLIT], lv[TSPLIT];
    float M = -1e30f;
#pragma unroll
    for (int s = 0; s < TSPLIT; ++s) {
        const float* mlb = ml + (size_t)((qtile * TSPLIT + s) * QBLK + rl) * 2;
        mv[s] = mlb[0];
        lv[s] = mlb[1];
        M = fmaxf(M, mv[s]);
    }
    float num = 0.f, den = 0.f;
#pragma unroll
    for (int s = 0; s < TSPLIT; ++s) {
        float w = EXP2(mv[s] - M);
        num += w * (float)Opart[((size_t)(qtile * TSPLIT + s) * QBLK + rl) * D_DIM + d];
        den += w * lv[s];
    }
    out[(size_t)r * D_DIM + d] = num / den;
}

extern "C" void kernel_launch(void* const* d_in, const int* in_sizes, int n_in,
                              void* d_out, int out_size, void* d_ws, size_t ws_size,
                              hipStream_t stream) {
    const float* Q = (const float*)d_in[0];
    const float* K = (const float*)d_in[1];
    const float* V = (const float*)d_in[2];
    float* out = (float*)d_out;
    char* ws = (char*)d_ws;

    _Float16* Qh = (_Float16*)ws;                    // 4MB row-major f16 (x log2e)
    _Float16* Kimg = (_Float16*)(ws + (4 << 20));    // 4MB linear-read 32-key tiles
    _Float16* Vimg = (_Float16*)(ws + (8 << 20));    // 4MB linear-read transposed tiles
    _Float16* Opart = (_Float16*)(ws + (12 << 20));  // 32MB f16 partials
    float* ml = (float*)(ws + ((size_t)44 << 20));   // 512KB

    // fused producer: 1024 Q-blocks + 1024 K-blocks + 256 V-blocks
    producer_kernel<<<2304, 256, 0, stream>>>(Q, K, V, Qh, Kimg, Vimg);

    // 512 blocks x 256 thr, 64KB dyn LDS -> 2 blocks/CU; bid&7 = split = XCD id
    attn_kernel<<<NQT * TSPLIT, 256, SMEM_BYTES, stream>>>(Qh, Kimg, Vimg, Opart, ml);
    combine_kernel<<<S_LEN, 256, 0, stream>>>(Opart, ml, out);
}